// Round 3
// baseline (801.047 us; speedup 1.0000x reference)
//
#include <hip/hip_runtime.h>
#include <cstdint>
#include <cstddef>

typedef unsigned short u16;
typedef __bf16 bf16x8 __attribute__((ext_vector_type(8)));
typedef float f32x4 __attribute__((ext_vector_type(4)));

#define EPS_ 1e-5f

// ---------- helpers ----------
__device__ __forceinline__ float bf2f(u16 u){
  union { uint32_t i; float f; } v; v.i = ((uint32_t)u) << 16; return v.f;
}
__device__ __forceinline__ u16 f2bf(float f){
  union { float f; uint32_t i; } v; v.f = f;
  uint32_t u = v.i;
  u += 0x7fffu + ((u >> 16) & 1u);   // round-to-nearest-even
  return (u16)(u >> 16);
}
__device__ __forceinline__ void gload_lds16(const void* g, void* l){
  __builtin_amdgcn_global_load_lds((const __attribute__((address_space(1))) uint32_t*)g,
                                   (__attribute__((address_space(3))) uint32_t*)l, 16, 0, 0);
}

// ---------- workspace offsets (bytes) — small buffers only (~36 MB total) ----------
#define OFF_WKV   ((size_t)0)            // 512*512*2 = 524288
#define OFF_WQB   ((size_t)524288)       // 131072
#define OFF_WOB   ((size_t)655360)       // 131072
#define OFF_BKV   ((size_t)786432)       // 2048 (pad)
#define OFF_A3DT  ((size_t)2097152)      // 32768*256*2 = 16777216
#define OFF_Q     ((size_t)18874368)     // 16777216  (end 35651584)

// large intermediates live in d_out's out1 region (268 MB, guaranteed size);
// k_resize_a4 overwrites the whole region LAST, after every reader finished (stream order)
#define OUT1_A4T  ((size_t)0)            // 33554432
#define OUT1_KV   ((size_t)33554432)     // 33554432
#define OUT1_ATT  ((size_t)67108864)     // 16777216
#define OUT1_PROJ ((size_t)83886080)     // 33554432 (f32)
#define OUT1_VK   ((size_t)117440512)    // 64*16*33*32*4 = 4325376 (f32 chunk partials)
#define OUT1_VKB  ((size_t)121765888)    // 64*48*32*2 = 196608    end 121962496 < 268435456

// ---------- weight folding: conv1x1 + BN into K/V projections ----------
__global__ __launch_bounds__(256) void k_fold(
    const float* __restrict__ conv_w, const float* __restrict__ conv_b,
    const float* __restrict__ bn_g, const float* __restrict__ bn_b,
    const float* __restrict__ bn_rm, const float* __restrict__ bn_rv,
    const float* __restrict__ wk, const float* __restrict__ bk,
    const float* __restrict__ wv, const float* __restrict__ bv,
    u16* __restrict__ WKV, float* __restrict__ bkv){
  int n = blockIdx.x;        // 0..511 : 0-255 K, 256-511 V
  int t = threadIdx.x;       // 256
  const float* wrow = (n < 256) ? (wk + (size_t)n*256) : (wv + (size_t)(n-256)*256);
  __shared__ float sw[256], st_[256];
  {
    float s  = bn_g[t] * rsqrtf(bn_rv[t] + EPS_);
    float tt = s * (conv_b[t] - bn_rm[t]) + bn_b[t];
    float w = wrow[t];
    sw[t] = w * s;
    st_[t] = w * tt;
  }
  __syncthreads();
  for (int cc = 0; cc < 2; ++cc){
    int c = t + cc*256;
    float acc = 0.f;
    #pragma unroll 8
    for (int o = 0; o < 256; ++o)
      acc += sw[o] * conv_w[(size_t)o*512 + c];
    WKV[(size_t)n*512 + c] = f2bf(acc);
  }
  if (t == 0){
    float acc = (n < 256) ? bk[n] : bv[n-256];
    for (int o = 0; o < 256; ++o) acc += st_[o];
    bkv[n] = acc;
  }
}

__global__ __launch_bounds__(256) void k_cvt(const float* __restrict__ src, u16* __restrict__ dst){
  int i = blockIdx.x*256 + threadIdx.x;
  dst[i] = f2bf(src[i]);
}

// ---------- a3 2x2 avg-pool + transpose to [b, p, c] bf16 ----------
__global__ __launch_bounds__(256) void k_pool_a3(const float* __restrict__ a3, u16* __restrict__ a3dT){
  int y = blockIdx.x;            // 0..63
  int c0 = blockIdx.y * 32;      // 8 tiles
  int b = blockIdx.z;
  int t = threadIdx.x;
  __shared__ float ld[32*257];
  const float* src = a3 + (((size_t)(b*256 + c0))*128 + 2*y)*128;
  #pragma unroll
  for (int cc = 0; cc < 32; ++cc)
    ld[cc*257 + t] = src[(size_t)cc*16384 + t];   // rows 2y,2y+1 contiguous (256 floats)
  __syncthreads();
  int cc = t & 31, xb = t >> 5;
  u16* dst = a3dT + ((size_t)b*4096 + y*64)*256 + c0 + cc;
  #pragma unroll
  for (int xi = 0; xi < 8; ++xi){
    int x = xb*8 + xi;
    const float* r = &ld[cc*257 + 2*x];
    float v = 0.25f*(r[0] + r[1] + r[128] + r[129]);
    dst[(size_t)x*256] = f2bf(v);
  }
}

// ---------- a4 transpose to [b, p, c] bf16 ----------
__global__ __launch_bounds__(256) void k_tr_a4(const float* __restrict__ a4, u16* __restrict__ a4T){
  int y = blockIdx.x;            // 0..63
  int c0 = blockIdx.y * 32;      // 16 tiles
  int b = blockIdx.z;
  int t = threadIdx.x;
  __shared__ float ld[32*65];
  const float* src = a4 + (((size_t)(b*512 + c0))*64 + y)*64;
  #pragma unroll
  for (int i = 0; i < 8; ++i){
    int idx = i*256 + t;
    int cc = idx >> 6, x = idx & 63;
    ld[cc*65 + x] = src[(size_t)cc*4096 + x];
  }
  __syncthreads();
  int cc = t & 31, xb = t >> 5;
  u16* dst = a4T + ((size_t)b*4096 + y*64)*512 + c0 + cc;
  #pragma unroll
  for (int xi = 0; xi < 8; ++xi){
    int x = xb*8 + xi;
    dst[(size_t)x*512] = f2bf(ld[cc*65 + x]);
  }
}

// ---------- bf16 MFMA GEMM: C[m,n] = A[m,:]·Bw[n,:] + bias[n] ----------
// SMODE 0: pos-major bf16 C[m*N + n]
// SMODE 1: channel-major bf16 C[(b*N + n)*4096 + p]   (m = b*4096 + p)
// SMODE 2: channel-major f32
template<int KDIM, int NDIM, int SMODE>
__global__ __launch_bounds__(256) void k_gemm(
    const u16* __restrict__ A, const u16* __restrict__ Bw,
    const float* __restrict__ bias, void* __restrict__ Cout){
  __shared__ alignas(16) u16 lA[128*32];
  __shared__ alignas(16) u16 lB[128*32];
  int m0 = blockIdx.x * 128, n0 = blockIdx.y * 128;
  int t = threadIdx.x;
  int lane = t & 63, wid = t >> 6;
  int wm = wid >> 1, wn = wid & 1;
  int fr = lane & 15, fq = lane >> 4;
  f32x4 acc[4][4] = {};
  const u16* Abase = A + (size_t)m0 * KDIM;
  const u16* Bbase = Bw + (size_t)n0 * KDIM;
  for (int kt = 0; kt < KDIM/32; ++kt){
    #pragma unroll
    for (int i = 0; i < 2; ++i){
      int u = i*256 + t;       // 16B unit within 8KB tile
      gload_lds16(Abase + (size_t)(u>>2)*KDIM + kt*32 + (u&3)*8, lA + u*8);
      gload_lds16(Bbase + (size_t)(u>>2)*KDIM + kt*32 + (u&3)*8, lB + u*8);
    }
    __syncthreads();
    bf16x8 af[4], bfr[4];
    #pragma unroll
    for (int fm = 0; fm < 4; ++fm)
      af[fm] = *(const bf16x8*)&lA[(wm*64 + fm*16 + fr)*32 + fq*8];
    #pragma unroll
    for (int fn = 0; fn < 4; ++fn)
      bfr[fn] = *(const bf16x8*)&lB[(wn*64 + fn*16 + fr)*32 + fq*8];
    #pragma unroll
    for (int fm = 0; fm < 4; ++fm)
      #pragma unroll
      for (int fn = 0; fn < 4; ++fn)
        acc[fm][fn] = __builtin_amdgcn_mfma_f32_16x16x32_bf16(af[fm], bfr[fn], acc[fm][fn], 0, 0, 0);
    __syncthreads();
  }
  #pragma unroll
  for (int fn = 0; fn < 4; ++fn){
    int j = n0 + wn*64 + fn*16 + fr;
    float bj = bias[j];
    #pragma unroll
    for (int fm = 0; fm < 4; ++fm){
      int m = m0 + wm*64 + fm*16 + fq*4;
      if constexpr (SMODE == 0){
        u16* C = (u16*)Cout;
        #pragma unroll
        for (int i = 0; i < 4; ++i)
          C[(size_t)(m + i)*NDIM + j] = f2bf(acc[fm][fn][i] + bj);
      } else {
        int b = m >> 12, p = m & 4095;
        size_t base = ((size_t)(b*NDIM + j))*4096 + p;
        if constexpr (SMODE == 1){
          u16* C = (u16*)Cout;
          ushort4 pk;
          pk.x = f2bf(acc[fm][fn][0] + bj);
          pk.y = f2bf(acc[fm][fn][1] + bj);
          pk.z = f2bf(acc[fm][fn][2] + bj);
          pk.w = f2bf(acc[fm][fn][3] + bj);
          *(ushort4*)&C[base] = pk;
        } else {
          float* C = (float*)Cout;
          float4 o4;
          o4.x = acc[fm][fn][0] + bj; o4.y = acc[fm][fn][1] + bj;
          o4.z = acc[fm][fn][2] + bj; o4.w = acc[fm][fn][3] + bj;
          *(float4*)&C[base] = o4;
        }
      }
    }
  }
}

// ---------- LayerNorm+ReLU, row-major [32768, 256], in place ----------
__global__ __launch_bounds__(256) void k_ln_row(u16* __restrict__ X,
    const float* __restrict__ g, const float* __restrict__ bb){
  int row = blockIdx.x*4 + (threadIdx.x >> 6);
  int lane = threadIdx.x & 63;
  u16* p = X + (size_t)row*256 + lane*4;
  ushort4 v4 = *(const ushort4*)p;
  float v0 = bf2f(v4.x), v1 = bf2f(v4.y), v2 = bf2f(v4.z), v3 = bf2f(v4.w);
  float s = v0+v1+v2+v3;
  float s2 = v0*v0+v1*v1+v2*v2+v3*v3;
  #pragma unroll
  for (int off = 32; off > 0; off >>= 1){
    s  += __shfl_down(s, off);
    s2 += __shfl_down(s2, off);
  }
  s = __shfl(s, 0); s2 = __shfl(s2, 0);
  float mean = s * (1.f/256.f);
  float var = s2 * (1.f/256.f) - mean*mean;
  float r = rsqrtf(var + EPS_);
  float4 gg = *(const float4*)&g[lane*4];
  float4 b4 = *(const float4*)&bb[lane*4];
  ushort4 o;
  o.x = f2bf(fmaxf((v0-mean)*r*gg.x + b4.x, 0.f));
  o.y = f2bf(fmaxf((v1-mean)*r*gg.y + b4.y, 0.f));
  o.z = f2bf(fmaxf((v2-mean)*r*gg.z + b4.z, 0.f));
  o.w = f2bf(fmaxf((v3-mean)*r*gg.w + b4.w, 0.f));
  *(ushort4*)p = o;
}

// ---------- LayerNorm+ReLU over channels, channel-major K part of KV, in place ----------
__global__ __launch_bounds__(256) void k_ln_col(u16* __restrict__ KV,
    const float* __restrict__ g, const float* __restrict__ bb){
  int p0 = blockIdx.x * 128;
  int b = blockIdx.y;
  int t = threadIdx.x;
  int pl = t & 127, jh = t >> 7;
  u16* base = KV + (size_t)b*512*4096 + p0 + pl;
  float s = 0.f, s2 = 0.f;
  for (int jj = 0; jj < 128; ++jj){
    float v = bf2f(base[(size_t)(jh*128 + jj)*4096]);
    s += v; s2 += v*v;
  }
  __shared__ float sh[2][2][128];
  sh[0][jh][pl] = s; sh[1][jh][pl] = s2;
  __syncthreads();
  float st = sh[0][0][pl] + sh[0][1][pl];
  float s2t = sh[1][0][pl] + sh[1][1][pl];
  float mean = st * (1.f/256.f);
  float var = s2t * (1.f/256.f) - mean*mean;
  float r = rsqrtf(var + EPS_);
  for (int jj = 0; jj < 128; ++jj){
    int j = jh*128 + jj;
    u16* q = base + (size_t)j*4096;
    float v = bf2f(*q);
    *q = f2bf(fmaxf((v - mean)*r*g[j] + bb[j], 0.f));
  }
}

// ---------- VK chunk partials: VKp[bh][chunk] = V'·K'^T over 256 n, + denom row ----------
__global__ __launch_bounds__(64) void k_vk(const u16* __restrict__ KV, float* __restrict__ VKp){
  int chunk = blockIdx.x;   // 16 chunks of 256 n
  int bh = blockIdx.y;      // b*8 + h
  int b = bh >> 3, h = bh & 7;
  int lane = threadIdx.x;
  __shared__ alignas(16) u16 lK[32*256];
  __shared__ alignas(16) u16 lV[32*256];
  int n0 = chunk * 256;
  const u16* Ks = KV + ((size_t)(b*512 + h*32))*4096 + n0;
  const u16* Vs = KV + ((size_t)(b*512 + 256 + h*32))*4096 + n0;
  #pragma unroll
  for (int i = 0; i < 16; ++i){
    int u = i*64 + lane;
    int row = u >> 5, cb = (u & 31)*8;
    gload_lds16(Ks + (size_t)row*4096 + cb, lK + u*8);
    gload_lds16(Vs + (size_t)row*4096 + cb, lV + u*8);
  }
  __builtin_amdgcn_s_waitcnt(0);
  __syncthreads();
  int fr = lane & 15, fq = lane >> 4;
  f32x4 acc[2][2] = {};
  #pragma unroll
  for (int ks = 0; ks < 8; ++ks){
    bf16x8 av0 = *(const bf16x8*)&lV[(fr)*256 + ks*32 + fq*8];
    bf16x8 av1 = *(const bf16x8*)&lV[(16+fr)*256 + ks*32 + fq*8];
    bf16x8 bk0 = *(const bf16x8*)&lK[(fr)*256 + ks*32 + fq*8];
    bf16x8 bk1 = *(const bf16x8*)&lK[(16+fr)*256 + ks*32 + fq*8];
    acc[0][0] = __builtin_amdgcn_mfma_f32_16x16x32_bf16(av0, bk0, acc[0][0], 0,0,0);
    acc[0][1] = __builtin_amdgcn_mfma_f32_16x16x32_bf16(av0, bk1, acc[0][1], 0,0,0);
    acc[1][0] = __builtin_amdgcn_mfma_f32_16x16x32_bf16(av1, bk0, acc[1][0], 0,0,0);
    acc[1][1] = __builtin_amdgcn_mfma_f32_16x16x32_bf16(av1, bk1, acc[1][1], 0,0,0);
  }
  float* dst = VKp + ((size_t)bh*16 + chunk)*(33*32);
  #pragma unroll
  for (int fe = 0; fe < 2; ++fe)
    #pragma unroll
    for (int fd = 0; fd < 2; ++fd)
      #pragma unroll
      for (int i = 0; i < 4; ++i){
        int e = fe*16 + fq*4 + i;
        int d = fd*16 + fr;
        dst[e*32 + d] = acc[fe][fd][i];
      }
  { // denominator partial: sum_n K[d, n] over this chunk
    int d = lane & 31, half = lane >> 5;
    float s = 0.f;
    #pragma unroll
    for (int i = 0; i < 16; ++i){
      bf16x8 kv = *(const bf16x8*)&lK[d*256 + half*128 + i*8];
      #pragma unroll
      for (int j = 0; j < 8; ++j) s += (float)kv[j];
    }
    s += __shfl_down(s, 32);
    if (lane < 32) dst[32*32 + d] = s;
  }
}

// ---------- reduce 16 chunk partials, convert to bf16 [bh][48][32] (rows 33..47 zero) ----------
__global__ __launch_bounds__(256) void k_cvt_vk(const float* __restrict__ VKp, u16* __restrict__ VKb){
  int i = blockIdx.x*256 + threadIdx.x;   // 64*48*32
  int bh = i / (48*32);
  int r = i - bh*48*32;
  int e = r >> 5, d = r & 31;
  float v = 0.f;
  if (e < 33){
    const float* p = VKp + (size_t)bh*16*(33*32) + e*32 + d;
    #pragma unroll
    for (int c = 0; c < 16; ++c) v += p[(size_t)c*(33*32)];
  }
  VKb[i] = f2bf(v);
}

// ---------- out = (VK·Q)/denom with the torch-faithful scrambled store ----------
__global__ __launch_bounds__(256) void k_att(const u16* __restrict__ Q,
    const u16* __restrict__ VKb, u16* __restrict__ ATT){
  int qc = blockIdx.x;     // 16 q-chunks of 256
  int bh = blockIdx.y;     // 64
  int b = bh >> 3, h = bh & 7;
  int t = threadIdx.x;
  int lane = t & 63, wid = t >> 6;
  int fr = lane & 15, fq = lane >> 4;
  int q0 = qc*256 + wid*64;
  const u16* Qb = Q + ((size_t)(b*4096 + q0))*256 + h*32 + fq*8;
  bf16x8 aq[4];
  #pragma unroll
  for (int fm = 0; fm < 4; ++fm)
    aq[fm] = *(const bf16x8*)&Qb[(size_t)(fm*16 + fr)*256];
  const u16* Vb = VKb + (size_t)bh*48*32;
  bf16x8 bv_[3];
  #pragma unroll
  for (int fn = 0; fn < 3; ++fn)
    bv_[fn] = *(const bf16x8*)&Vb[(fn*16 + fr)*32 + fq*8];
  f32x4 acc[4][3] = {};
  #pragma unroll
  for (int fm = 0; fm < 4; ++fm)
    #pragma unroll
    for (int fn = 0; fn < 3; ++fn)
      acc[fm][fn] = __builtin_amdgcn_mfma_f32_16x16x32_bf16(aq[fm], bv_[fn], acc[fm][fn], 0,0,0);
  __shared__ alignas(16) u16 latt[32*264];
  #pragma unroll
  for (int fm = 0; fm < 4; ++fm){
    #pragma unroll
    for (int i = 0; i < 4; ++i){
      float dv = __shfl(acc[fm][2][i], lane & 48);   // e=32 value lives in fr==0 lane of my fq group
      float rd = 1.0f / fmaxf(dv, EPS_);
      int qloc = wid*64 + fm*16 + fq*4 + i;
      latt[(fr)*264 + qloc]      = f2bf(acc[fm][0][i] * rd);
      latt[(16 + fr)*264 + qloc] = f2bf(acc[fm][1][i] * rd);
    }
  }
  __syncthreads();
  // scrambled reshape: (e,h,q) -> row 128e + 16h + (q>>8), col q&255
  int row = t >> 3, seg = t & 7;
  u16* dst = ATT + ((size_t)(b*4096 + row*128 + h*16 + qc))*256 + seg*32;
  const u16* srcl = &latt[row*264 + seg*32];
  #pragma unroll
  for (int k = 0; k < 4; ++k)
    *(uint4*)&dst[k*8] = *(const uint4*)&srcl[k*8];
}

// ---------- bilinear 2x upsample (jax half-pixel, edge-renormalized) ----------
__device__ __forceinline__ void bil_idx(int o, int n, int &i0, int &i1, float &w0, float &w1){
  float s = 0.5f*(float)o - 0.25f;
  float fl = floorf(s);
  i0 = (int)fl; i1 = i0 + 1;
  w1 = s - fl; w0 = 1.f - w1;
  if (i0 < 0){ i0 = 0; w0 = 0.f; w1 = 1.f; }
  if (i1 > n-1){ i1 = n-1; w1 = 0.f; w0 = 1.f; }
}

__global__ __launch_bounds__(256) void k_resize_mul_a3(const float* __restrict__ PROJ,
    const float* __restrict__ a3, float* __restrict__ out0){
  int bc = blockIdx.x;   // b*256 + ch
  int t = threadIdx.x;
  __shared__ float P[4096];
  const float* src = PROJ + (size_t)bc*4096;
  #pragma unroll
  for (int i = 0; i < 16; ++i) P[i*256 + t] = src[i*256 + t];
  __syncthreads();
  const float* ap = a3 + (size_t)bc*16384;
  float* op = out0 + (size_t)bc*16384;
  for (int k = 0; k < 64; ++k){
    int px = k*256 + t;
    int Y = px >> 7, X = px & 127;
    int y0,y1,x0,x1; float wy0,wy1,wx0,wx1;
    bil_idx(Y, 64, y0,y1,wy0,wy1);
    bil_idx(X, 64, x0,x1,wx0,wx1);
    float v = wy0*(wx0*P[y0*64+x0] + wx1*P[y0*64+x1])
            + wy1*(wx0*P[y1*64+x0] + wx1*P[y1*64+x1]);
    op[px] = v * ap[px];
  }
}

__global__ __launch_bounds__(256) void k_resize_a4(const float* __restrict__ a4, float* __restrict__ out1){
  int bc = blockIdx.x;   // b*512 + c
  int t = threadIdx.x;
  __shared__ float P[4096];
  const float* src = a4 + (size_t)bc*4096;
  #pragma unroll
  for (int i = 0; i < 16; ++i) P[i*256 + t] = src[i*256 + t];
  __syncthreads();
  float* op = out1 + (size_t)bc*16384;
  for (int k = 0; k < 64; ++k){
    int px = k*256 + t;
    int Y = px >> 7, X = px & 127;
    int y0,y1,x0,x1; float wy0,wy1,wx0,wx1;
    bil_idx(Y, 64, y0,y1,wy0,wy1);
    bil_idx(X, 64, x0,x1,wx0,wx1);
    op[px] = wy0*(wx0*P[y0*64+x0] + wx1*P[y0*64+x1])
           + wy1*(wx0*P[y1*64+x0] + wx1*P[y1*64+x1]);
  }
}

// ---------- host launch ----------
extern "C" void kernel_launch(void* const* d_in, const int* in_sizes, int n_in,
                              void* d_out, int out_size, void* d_ws, size_t ws_size,
                              hipStream_t stream){
  (void)in_sizes; (void)n_in; (void)out_size; (void)ws_size;
  const float* a3     = (const float*)d_in[0];
  const float* a4     = (const float*)d_in[1];
  const float* conv_w = (const float*)d_in[2];
  const float* conv_b = (const float*)d_in[3];
  const float* bn_g   = (const float*)d_in[4];
  const float* bn_b   = (const float*)d_in[5];
  const float* bn_rm  = (const float*)d_in[6];
  const float* bn_rv  = (const float*)d_in[7];
  const float* wq     = (const float*)d_in[8];
  const float* bq     = (const float*)d_in[9];
  const float* lnq_g  = (const float*)d_in[10];
  const float* lnq_b  = (const float*)d_in[11];
  const float* wk     = (const float*)d_in[12];
  const float* bk     = (const float*)d_in[13];
  const float* lnk_g  = (const float*)d_in[14];
  const float* lnk_b  = (const float*)d_in[15];
  const float* wv     = (const float*)d_in[16];
  const float* bv     = (const float*)d_in[17];
  const float* wo     = (const float*)d_in[18];
  const float* bo     = (const float*)d_in[19];
  // d_in[20..27] (FFN weights/norms) are dead code in the reference; d_in[28] = idx (always 11)

  float* out0 = (float*)d_out;
  float* out1 = out0 + (size_t)33554432;

  char* ws = (char*)d_ws;
  u16*   WKV  = (u16*)(ws + OFF_WKV);
  u16*   WQB  = (u16*)(ws + OFF_WQB);
  u16*   WOB  = (u16*)(ws + OFF_WOB);
  float* BKV  = (float*)(ws + OFF_BKV);
  u16*   A3DT = (u16*)(ws + OFF_A3DT);
  u16*   Qw   = (u16*)(ws + OFF_Q);

  // large intermediates in the out1 region (overwritten by k_resize_a4 at the very end)
  char* o1 = (char*)out1;
  u16*   A4T  = (u16*)(o1 + OUT1_A4T);
  u16*   KVw  = (u16*)(o1 + OUT1_KV);
  u16*   ATT  = (u16*)(o1 + OUT1_ATT);
  float* PROJ = (float*)(o1 + OUT1_PROJ);
  float* VKp  = (float*)(o1 + OUT1_VK);
  u16*   VKB  = (u16*)(o1 + OUT1_VKB);

  // weight prep
  k_fold<<<512, 256, 0, stream>>>(conv_w, conv_b, bn_g, bn_b, bn_rm, bn_rv,
                                  wk, bk, wv, bv, WKV, BKV);
  k_cvt<<<256, 256, 0, stream>>>(wq, WQB);
  k_cvt<<<256, 256, 0, stream>>>(wo, WOB);

  // input reshapes
  k_pool_a3<<<dim3(64, 8, 8), 256, 0, stream>>>(a3, A3DT);
  k_tr_a4<<<dim3(64, 16, 8), 256, 0, stream>>>(a4, A4T);

  // projections
  k_gemm<256, 256, 0><<<dim3(256, 2), 256, 0, stream>>>(A3DT, WQB, bq, (void*)Qw);
  k_gemm<512, 512, 1><<<dim3(256, 4), 256, 0, stream>>>(A4T, WKV, BKV, (void*)KVw);

  // norms (+ReLU)
  k_ln_row<<<8192, 256, 0, stream>>>(Qw, lnq_g, lnq_b);
  k_ln_col<<<dim3(32, 8), 256, 0, stream>>>(KVw, lnk_g, lnk_b);

  // attention (deterministic: per-chunk partials + reduction, no atomics/memset)
  k_vk<<<dim3(16, 64), 64, 0, stream>>>(KVw, VKp);
  k_cvt_vk<<<384, 256, 0, stream>>>(VKp, VKB);
  k_att<<<dim3(16, 64), 256, 0, stream>>>(Qw, VKB, ATT);

  // output projection (channel-major f32)
  k_gemm<256, 256, 2><<<dim3(256, 2), 256, 0, stream>>>(ATT, WOB, bo, (void*)PROJ);

  // outputs
  k_resize_mul_a3<<<2048, 256, 0, stream>>>(PROJ, a3, out0);
  k_resize_a4<<<4096, 256, 0, stream>>>(a4, out1);
}

// Round 4
// 785.523 us; speedup vs baseline: 1.0198x; 1.0198x over previous
//
#include <hip/hip_runtime.h>
#include <cstdint>
#include <cstddef>

typedef unsigned short u16;
typedef __bf16 bf16x8 __attribute__((ext_vector_type(8)));
typedef float f32x4 __attribute__((ext_vector_type(4)));

#define EPS_ 1e-5f

// ---------- helpers ----------
__device__ __forceinline__ float bf2f(u16 u){
  union { uint32_t i; float f; } v; v.i = ((uint32_t)u) << 16; return v.f;
}
__device__ __forceinline__ u16 f2bf(float f){
  union { float f; uint32_t i; } v; v.f = f;
  uint32_t u = v.i;
  u += 0x7fffu + ((u >> 16) & 1u);   // round-to-nearest-even
  return (u16)(u >> 16);
}
__device__ __forceinline__ void gload_lds16(const void* g, void* l){
  __builtin_amdgcn_global_load_lds((const __attribute__((address_space(1))) uint32_t*)g,
                                   (__attribute__((address_space(3))) uint32_t*)l, 16, 0, 0);
}

// ---------- workspace offsets (bytes) — small buffers only (~36 MB total) ----------
#define OFF_WKV   ((size_t)0)            // 512*512*2 = 524288
#define OFF_WQB   ((size_t)524288)       // 131072
#define OFF_WOB   ((size_t)655360)       // 131072
#define OFF_BKV   ((size_t)786432)       // 2048 (pad)
#define OFF_A3DT  ((size_t)2097152)      // 32768*256*2 = 16777216
#define OFF_Q     ((size_t)18874368)     // 16777216  (end 35651584)

// large intermediates live in d_out's out1 region (268 MB, guaranteed size);
// k_resize_a4 overwrites the whole region LAST, after every reader finished (stream order)
#define OUT1_A4T  ((size_t)0)            // 33554432
#define OUT1_KV   ((size_t)33554432)     // 33554432
#define OUT1_ATT  ((size_t)67108864)     // 16777216
#define OUT1_PROJ ((size_t)83886080)     // 16777216 (bf16 now)
#define OUT1_VK   ((size_t)117440512)    // 64*16*33*32*4 = 4325376 (f32 chunk partials)
#define OUT1_VKB  ((size_t)121765888)    // 64*48*32*2 = 196608    end 121962496 < 268435456

// ---------- weight folding: conv1x1 + BN into K/V projections ----------
__global__ __launch_bounds__(256) void k_fold(
    const float* __restrict__ conv_w, const float* __restrict__ conv_b,
    const float* __restrict__ bn_g, const float* __restrict__ bn_b,
    const float* __restrict__ bn_rm, const float* __restrict__ bn_rv,
    const float* __restrict__ wk, const float* __restrict__ bk,
    const float* __restrict__ wv, const float* __restrict__ bv,
    u16* __restrict__ WKV, float* __restrict__ bkv){
  int n = blockIdx.x;        // 0..511 : 0-255 K, 256-511 V
  int t = threadIdx.x;       // 256
  const float* wrow = (n < 256) ? (wk + (size_t)n*256) : (wv + (size_t)(n-256)*256);
  __shared__ float sw[256], st_[256];
  {
    float s  = bn_g[t] * rsqrtf(bn_rv[t] + EPS_);
    float tt = s * (conv_b[t] - bn_rm[t]) + bn_b[t];
    float w = wrow[t];
    sw[t] = w * s;
    st_[t] = w * tt;
  }
  __syncthreads();
  for (int cc = 0; cc < 2; ++cc){
    int c = t + cc*256;
    float acc = 0.f;
    #pragma unroll 8
    for (int o = 0; o < 256; ++o)
      acc += sw[o] * conv_w[(size_t)o*512 + c];
    WKV[(size_t)n*512 + c] = f2bf(acc);
  }
  if (t == 0){
    float acc = (n < 256) ? bk[n] : bv[n-256];
    for (int o = 0; o < 256; ++o) acc += st_[o];
    bkv[n] = acc;
  }
}

// convert wq (blocks 0..255) and wo (blocks 256..511) to bf16 in one launch
__global__ __launch_bounds__(256) void k_cvt2(const float* __restrict__ wq, const float* __restrict__ wo,
                                              u16* __restrict__ WQB, u16* __restrict__ WOB){
  int bidx = blockIdx.x;
  const float* src = (bidx < 256) ? wq : wo;
  u16* dst = (bidx < 256) ? WQB : WOB;
  int i = (bidx & 255)*256 + threadIdx.x;
  dst[i] = f2bf(src[i]);
}

// ---------- a3 2x2 avg-pool + transpose to [b, p, c] bf16 ----------
__global__ __launch_bounds__(256) void k_pool_a3(const float* __restrict__ a3, u16* __restrict__ a3dT){
  int y = blockIdx.x;            // 0..63
  int c0 = blockIdx.y * 32;      // 8 tiles
  int b = blockIdx.z;
  int t = threadIdx.x;
  __shared__ float ld[32*257];
  const float* src = a3 + (((size_t)(b*256 + c0))*128 + 2*y)*128;
  #pragma unroll
  for (int cc = 0; cc < 32; ++cc)
    ld[cc*257 + t] = src[(size_t)cc*16384 + t];   // rows 2y,2y+1 contiguous (256 floats)
  __syncthreads();
  int cc = t & 31, xb = t >> 5;
  u16* dst = a3dT + ((size_t)b*4096 + y*64)*256 + c0 + cc;
  #pragma unroll
  for (int xi = 0; xi < 8; ++xi){
    int x = xb*8 + xi;
    const float* r = &ld[cc*257 + 2*x];
    float v = 0.25f*(r[0] + r[1] + r[128] + r[129]);
    dst[(size_t)x*256] = f2bf(v);
  }
}

// ---------- a4 transpose to [b, p, c] bf16 ----------
__global__ __launch_bounds__(256) void k_tr_a4(const float* __restrict__ a4, u16* __restrict__ a4T){
  int y = blockIdx.x;            // 0..63
  int c0 = blockIdx.y * 32;      // 16 tiles
  int b = blockIdx.z;
  int t = threadIdx.x;
  __shared__ float ld[32*65];
  const float* src = a4 + (((size_t)(b*512 + c0))*64 + y)*64;
  #pragma unroll
  for (int i = 0; i < 8; ++i){
    int idx = i*256 + t;
    int cc = idx >> 6, x = idx & 63;
    ld[cc*65 + x] = src[(size_t)cc*4096 + x];
  }
  __syncthreads();
  int cc = t & 31, xb = t >> 5;
  u16* dst = a4T + ((size_t)b*4096 + y*64)*512 + c0 + cc;
  #pragma unroll
  for (int xi = 0; xi < 8; ++xi){
    int x = xb*8 + xi;
    dst[(size_t)x*512] = f2bf(ld[cc*65 + x]);
  }
}

// ---------- bf16 MFMA GEMM: C[m,n] = A[m,:]·Bw[n,:] + bias[n] ----------
// SMODE 0: pos-major bf16 C[m*N + n]
// SMODE 1: channel-major bf16 C[(b*N + n)*4096 + p]   (m = b*4096 + p)
template<int KDIM, int NDIM, int SMODE>
__global__ __launch_bounds__(256) void k_gemm(
    const u16* __restrict__ A, const u16* __restrict__ Bw,
    const float* __restrict__ bias, void* __restrict__ Cout){
  __shared__ alignas(16) u16 lA[128*32];
  __shared__ alignas(16) u16 lB[128*32];
  int m0 = blockIdx.x * 128, n0 = blockIdx.y * 128;
  int t = threadIdx.x;
  int lane = t & 63, wid = t >> 6;
  int wm = wid >> 1, wn = wid & 1;
  int fr = lane & 15, fq = lane >> 4;
  f32x4 acc[4][4] = {};
  const u16* Abase = A + (size_t)m0 * KDIM;
  const u16* Bbase = Bw + (size_t)n0 * KDIM;
  for (int kt = 0; kt < KDIM/32; ++kt){
    #pragma unroll
    for (int i = 0; i < 2; ++i){
      int u = i*256 + t;       // 16B unit within 8KB tile
      gload_lds16(Abase + (size_t)(u>>2)*KDIM + kt*32 + (u&3)*8, lA + u*8);
      gload_lds16(Bbase + (size_t)(u>>2)*KDIM + kt*32 + (u&3)*8, lB + u*8);
    }
    __syncthreads();
    bf16x8 af[4], bfr[4];
    #pragma unroll
    for (int fm = 0; fm < 4; ++fm)
      af[fm] = *(const bf16x8*)&lA[(wm*64 + fm*16 + fr)*32 + fq*8];
    #pragma unroll
    for (int fn = 0; fn < 4; ++fn)
      bfr[fn] = *(const bf16x8*)&lB[(wn*64 + fn*16 + fr)*32 + fq*8];
    #pragma unroll
    for (int fm = 0; fm < 4; ++fm)
      #pragma unroll
      for (int fn = 0; fn < 4; ++fn)
        acc[fm][fn] = __builtin_amdgcn_mfma_f32_16x16x32_bf16(af[fm], bfr[fn], acc[fm][fn], 0, 0, 0);
    __syncthreads();
  }
  #pragma unroll
  for (int fn = 0; fn < 4; ++fn){
    int j = n0 + wn*64 + fn*16 + fr;
    float bj = bias[j];
    #pragma unroll
    for (int fm = 0; fm < 4; ++fm){
      int m = m0 + wm*64 + fm*16 + fq*4;
      if constexpr (SMODE == 0){
        u16* C = (u16*)Cout;
        #pragma unroll
        for (int i = 0; i < 4; ++i)
          C[(size_t)(m + i)*NDIM + j] = f2bf(acc[fm][fn][i] + bj);
      } else {
        int b = m >> 12, p = m & 4095;
        size_t base = ((size_t)(b*NDIM + j))*4096 + p;
        u16* C = (u16*)Cout;
        ushort4 pk;
        pk.x = f2bf(acc[fm][fn][0] + bj);
        pk.y = f2bf(acc[fm][fn][1] + bj);
        pk.z = f2bf(acc[fm][fn][2] + bj);
        pk.w = f2bf(acc[fm][fn][3] + bj);
        *(ushort4*)&C[base] = pk;
      }
    }
  }
}

// ---------- LayerNorm+ReLU, row-major [32768, 256], in place ----------
__global__ __launch_bounds__(256) void k_ln_row(u16* __restrict__ X,
    const float* __restrict__ g, const float* __restrict__ bb){
  int row = blockIdx.x*4 + (threadIdx.x >> 6);
  int lane = threadIdx.x & 63;
  u16* p = X + (size_t)row*256 + lane*4;
  ushort4 v4 = *(const ushort4*)p;
  float v0 = bf2f(v4.x), v1 = bf2f(v4.y), v2 = bf2f(v4.z), v3 = bf2f(v4.w);
  float s = v0+v1+v2+v3;
  float s2 = v0*v0+v1*v1+v2*v2+v3*v3;
  #pragma unroll
  for (int off = 32; off > 0; off >>= 1){
    s  += __shfl_down(s, off);
    s2 += __shfl_down(s2, off);
  }
  s = __shfl(s, 0); s2 = __shfl(s2, 0);
  float mean = s * (1.f/256.f);
  float var = s2 * (1.f/256.f) - mean*mean;
  float r = rsqrtf(var + EPS_);
  float4 gg = *(const float4*)&g[lane*4];
  float4 b4 = *(const float4*)&bb[lane*4];
  ushort4 o;
  o.x = f2bf(fmaxf((v0-mean)*r*gg.x + b4.x, 0.f));
  o.y = f2bf(fmaxf((v1-mean)*r*gg.y + b4.y, 0.f));
  o.z = f2bf(fmaxf((v2-mean)*r*gg.z + b4.z, 0.f));
  o.w = f2bf(fmaxf((v3-mean)*r*gg.w + b4.w, 0.f));
  *(ushort4*)p = o;
}

// ---------- LayerNorm+ReLU over channels (K half of KV), LDS-staged, coalesced ----------
// grid: (32 p-chunks of 128, 8 b), block 256. Tile [256 j][128 p] u16 in LDS (padded 132).
__global__ __launch_bounds__(256) void k_ln_col(u16* __restrict__ KV,
    const float* __restrict__ g, const float* __restrict__ bb){
  int p0 = blockIdx.x * 128;
  int b = blockIdx.y;
  int t = threadIdx.x;
  __shared__ uint32_t lds32[256*66];     // [256 rows][66 u32] = 67.6 KB
  __shared__ float sA[256], sB[256];
  __shared__ float meanA[128], rstdA[128];
  u16* tile = (u16*)lds32;
  int c = t & 63;                        // u32 col (fixed per thread)
  int w = t >> 6;                        // wave id 0..3
  // load: 64 iterations, each wave reads one full 256B row (64 u32 coalesced)
  #pragma unroll 8
  for (int i = 0; i < 64; ++i){
    int j = i*4 + w;
    uint32_t v = ((const uint32_t*)(KV + ((size_t)(b*512 + j))*4096 + p0))[c];
    lds32[j*66 + c] = v;
  }
  __syncthreads();
  // stats: thread owns p = t&127, half jh = t>>7 (128 j each)
  {
    int p = t & 127, jh = t >> 7;
    float s = 0.f, s2 = 0.f;
    #pragma unroll 8
    for (int jj = 0; jj < 128; ++jj){
      float v = bf2f(tile[(jh*128 + jj)*132 + p]);
      s += v; s2 += v*v;
    }
    sA[t] = s; sB[t] = s2;
  }
  __syncthreads();
  if (t < 128){
    float st = sA[t] + sA[128 + t];
    float s2t = sB[t] + sB[128 + t];
    float mean = st * (1.f/256.f);
    float var = s2t * (1.f/256.f) - mean*mean;
    meanA[t] = mean;
    rstdA[t] = rsqrtf(var + EPS_);
  }
  __syncthreads();
  // apply: same coalesced pattern as load; per-thread p-pair stats loaded once
  float m0v = meanA[2*c], m1v = meanA[2*c + 1];
  float r0 = rstdA[2*c], r1 = rstdA[2*c + 1];
  #pragma unroll 8
  for (int i = 0; i < 64; ++i){
    int j = i*4 + w;
    uint32_t v = lds32[j*66 + c];
    float v0 = bf2f((u16)(v & 0xffffu));
    float v1 = bf2f((u16)(v >> 16));
    float gj = g[j], bj = bb[j];
    u16 o0 = f2bf(fmaxf((v0 - m0v)*r0*gj + bj, 0.f));
    u16 o1 = f2bf(fmaxf((v1 - m1v)*r1*gj + bj, 0.f));
    ((uint32_t*)(KV + ((size_t)(b*512 + j))*4096 + p0))[c] = (uint32_t)o0 | ((uint32_t)o1 << 16);
  }
}

// ---------- VK chunk partials: VKp[bh][chunk] = V'·K'^T over 256 n, + denom row ----------
__global__ __launch_bounds__(64) void k_vk(const u16* __restrict__ KV, float* __restrict__ VKp){
  int chunk = blockIdx.x;   // 16 chunks of 256 n
  int bh = blockIdx.y;      // b*8 + h
  int b = bh >> 3, h = bh & 7;
  int lane = threadIdx.x;
  __shared__ alignas(16) u16 lK[32*256];
  __shared__ alignas(16) u16 lV[32*256];
  int n0 = chunk * 256;
  const u16* Ks = KV + ((size_t)(b*512 + h*32))*4096 + n0;
  const u16* Vs = KV + ((size_t)(b*512 + 256 + h*32))*4096 + n0;
  #pragma unroll
  for (int i = 0; i < 16; ++i){
    int u = i*64 + lane;
    int row = u >> 5, cb = (u & 31)*8;
    gload_lds16(Ks + (size_t)row*4096 + cb, lK + u*8);
    gload_lds16(Vs + (size_t)row*4096 + cb, lV + u*8);
  }
  __builtin_amdgcn_s_waitcnt(0);
  __syncthreads();
  int fr = lane & 15, fq = lane >> 4;
  f32x4 acc[2][2] = {};
  #pragma unroll
  for (int ks = 0; ks < 8; ++ks){
    bf16x8 av0 = *(const bf16x8*)&lV[(fr)*256 + ks*32 + fq*8];
    bf16x8 av1 = *(const bf16x8*)&lV[(16+fr)*256 + ks*32 + fq*8];
    bf16x8 bk0 = *(const bf16x8*)&lK[(fr)*256 + ks*32 + fq*8];
    bf16x8 bk1 = *(const bf16x8*)&lK[(16+fr)*256 + ks*32 + fq*8];
    acc[0][0] = __builtin_amdgcn_mfma_f32_16x16x32_bf16(av0, bk0, acc[0][0], 0,0,0);
    acc[0][1] = __builtin_amdgcn_mfma_f32_16x16x32_bf16(av0, bk1, acc[0][1], 0,0,0);
    acc[1][0] = __builtin_amdgcn_mfma_f32_16x16x32_bf16(av1, bk0, acc[1][0], 0,0,0);
    acc[1][1] = __builtin_amdgcn_mfma_f32_16x16x32_bf16(av1, bk1, acc[1][1], 0,0,0);
  }
  float* dst = VKp + ((size_t)bh*16 + chunk)*(33*32);
  #pragma unroll
  for (int fe = 0; fe < 2; ++fe)
    #pragma unroll
    for (int fd = 0; fd < 2; ++fd)
      #pragma unroll
      for (int i = 0; i < 4; ++i){
        int e = fe*16 + fq*4 + i;
        int d = fd*16 + fr;
        dst[e*32 + d] = acc[fe][fd][i];
      }
  { // denominator partial: sum_n K[d, n] over this chunk
    int d = lane & 31, half = lane >> 5;
    float s = 0.f;
    #pragma unroll
    for (int i = 0; i < 16; ++i){
      bf16x8 kv = *(const bf16x8*)&lK[d*256 + half*128 + i*8];
      #pragma unroll
      for (int j = 0; j < 8; ++j) s += (float)kv[j];
    }
    s += __shfl_down(s, 32);
    if (lane < 32) dst[32*32 + d] = s;
  }
}

// ---------- reduce 16 chunk partials, convert to bf16 [bh][48][32] (rows 33..47 zero) ----------
__global__ __launch_bounds__(256) void k_cvt_vk(const float* __restrict__ VKp, u16* __restrict__ VKb){
  int i = blockIdx.x*256 + threadIdx.x;   // 64*48*32
  int bh = i / (48*32);
  int r = i - bh*48*32;
  int e = r >> 5, d = r & 31;
  float v = 0.f;
  if (e < 33){
    const float* p = VKp + (size_t)bh*16*(33*32) + e*32 + d;
    #pragma unroll
    for (int c = 0; c < 16; ++c) v += p[(size_t)c*(33*32)];
  }
  VKb[i] = f2bf(v);
}

// ---------- out = (VK·Q)/denom with the torch-faithful scrambled store ----------
__global__ __launch_bounds__(256) void k_att(const u16* __restrict__ Q,
    const u16* __restrict__ VKb, u16* __restrict__ ATT){
  int qc = blockIdx.x;     // 16 q-chunks of 256
  int bh = blockIdx.y;     // 64
  int b = bh >> 3, h = bh & 7;
  int t = threadIdx.x;
  int lane = t & 63, wid = t >> 6;
  int fr = lane & 15, fq = lane >> 4;
  int q0 = qc*256 + wid*64;
  const u16* Qb = Q + ((size_t)(b*4096 + q0))*256 + h*32 + fq*8;
  bf16x8 aq[4];
  #pragma unroll
  for (int fm = 0; fm < 4; ++fm)
    aq[fm] = *(const bf16x8*)&Qb[(size_t)(fm*16 + fr)*256];
  const u16* Vb = VKb + (size_t)bh*48*32;
  bf16x8 bv_[3];
  #pragma unroll
  for (int fn = 0; fn < 3; ++fn)
    bv_[fn] = *(const bf16x8*)&Vb[(fn*16 + fr)*32 + fq*8];
  f32x4 acc[4][3] = {};
  #pragma unroll
  for (int fm = 0; fm < 4; ++fm)
    #pragma unroll
    for (int fn = 0; fn < 3; ++fn)
      acc[fm][fn] = __builtin_amdgcn_mfma_f32_16x16x32_bf16(aq[fm], bv_[fn], acc[fm][fn], 0,0,0);
  __shared__ alignas(16) u16 latt[32*264];
  #pragma unroll
  for (int fm = 0; fm < 4; ++fm){
    #pragma unroll
    for (int i = 0; i < 4; ++i){
      float dv = __shfl(acc[fm][2][i], lane & 48);   // e=32 value lives in fr==0 lane of my fq group
      float rd = 1.0f / fmaxf(dv, EPS_);
      int qloc = wid*64 + fm*16 + fq*4 + i;
      latt[(fr)*264 + qloc]      = f2bf(acc[fm][0][i] * rd);
      latt[(16 + fr)*264 + qloc] = f2bf(acc[fm][1][i] * rd);
    }
  }
  __syncthreads();
  // scrambled reshape: (e,h,q) -> row 128e + 16h + (q>>8), col q&255
  int row = t >> 3, seg = t & 7;
  u16* dst = ATT + ((size_t)(b*4096 + row*128 + h*16 + qc))*256 + seg*32;
  const u16* srcl = &latt[row*264 + seg*32];
  #pragma unroll
  for (int k = 0; k < 4; ++k)
    *(uint4*)&dst[k*8] = *(const uint4*)&srcl[k*8];
}

// ---------- bilinear 2x upsample (jax half-pixel, edge-renormalized) ----------
__device__ __forceinline__ void bil_idx(int o, int n, int &i0, int &i1, float &w0, float &w1){
  float s = 0.5f*(float)o - 0.25f;
  float fl = floorf(s);
  i0 = (int)fl; i1 = i0 + 1;
  w1 = s - fl; w0 = 1.f - w1;
  if (i0 < 0){ i0 = 0; w0 = 0.f; w1 = 1.f; }
  if (i1 > n-1){ i1 = n-1; w1 = 0.f; w0 = 1.f; }
}

__global__ __launch_bounds__(256) void k_resize_mul_a3(const u16* __restrict__ PROJ,
    const float* __restrict__ a3, float* __restrict__ out0){
  int bc = blockIdx.x;   // b*256 + ch
  int t = threadIdx.x;
  __shared__ float P[4096];
  const uint32_t* src = (const uint32_t*)(PROJ + (size_t)bc*4096);
  #pragma unroll
  for (int i = 0; i < 8; ++i){
    uint32_t v = src[i*256 + t];
    P[(i*256 + t)*2]     = bf2f((u16)(v & 0xffffu));
    P[(i*256 + t)*2 + 1] = bf2f((u16)(v >> 16));
  }
  __syncthreads();
  const float* ap = a3 + (size_t)bc*16384;
  float* op = out0 + (size_t)bc*16384;
  for (int k = 0; k < 64; ++k){
    int px = k*256 + t;
    int Y = px >> 7, X = px & 127;
    int y0,y1,x0,x1; float wy0,wy1,wx0,wx1;
    bil_idx(Y, 64, y0,y1,wy0,wy1);
    bil_idx(X, 64, x0,x1,wx0,wx1);
    float v = wy0*(wx0*P[y0*64+x0] + wx1*P[y0*64+x1])
            + wy1*(wx0*P[y1*64+x0] + wx1*P[y1*64+x1]);
    op[px] = v * ap[px];
  }
}

__global__ __launch_bounds__(256) void k_resize_a4(const float* __restrict__ a4, float* __restrict__ out1){
  int bc = blockIdx.x;   // b*512 + c
  int t = threadIdx.x;
  __shared__ float P[4096];
  const float* src = a4 + (size_t)bc*4096;
  #pragma unroll
  for (int i = 0; i < 16; ++i) P[i*256 + t] = src[i*256 + t];
  __syncthreads();
  float* op = out1 + (size_t)bc*16384;
  for (int k = 0; k < 64; ++k){
    int px = k*256 + t;
    int Y = px >> 7, X = px & 127;
    int y0,y1,x0,x1; float wy0,wy1,wx0,wx1;
    bil_idx(Y, 64, y0,y1,wy0,wy1);
    bil_idx(X, 64, x0,x1,wx0,wx1);
    op[px] = wy0*(wx0*P[y0*64+x0] + wx1*P[y0*64+x1])
           + wy1*(wx0*P[y1*64+x0] + wx1*P[y1*64+x1]);
  }
}

// ---------- host launch ----------
extern "C" void kernel_launch(void* const* d_in, const int* in_sizes, int n_in,
                              void* d_out, int out_size, void* d_ws, size_t ws_size,
                              hipStream_t stream){
  (void)in_sizes; (void)n_in; (void)out_size; (void)ws_size;
  const float* a3     = (const float*)d_in[0];
  const float* a4     = (const float*)d_in[1];
  const float* conv_w = (const float*)d_in[2];
  const float* conv_b = (const float*)d_in[3];
  const float* bn_g   = (const float*)d_in[4];
  const float* bn_b   = (const float*)d_in[5];
  const float* bn_rm  = (const float*)d_in[6];
  const float* bn_rv  = (const float*)d_in[7];
  const float* wq     = (const float*)d_in[8];
  const float* bq     = (const float*)d_in[9];
  const float* lnq_g  = (const float*)d_in[10];
  const float* lnq_b  = (const float*)d_in[11];
  const float* wk     = (const float*)d_in[12];
  const float* bk     = (const float*)d_in[13];
  const float* lnk_g  = (const float*)d_in[14];
  const float* lnk_b  = (const float*)d_in[15];
  const float* wv     = (const float*)d_in[16];
  const float* bv     = (const float*)d_in[17];
  const float* wo     = (const float*)d_in[18];
  const float* bo     = (const float*)d_in[19];
  // d_in[20..27] (FFN weights/norms) are dead code in the reference; d_in[28] = idx (always 11)

  float* out0 = (float*)d_out;
  float* out1 = out0 + (size_t)33554432;

  char* ws = (char*)d_ws;
  u16*   WKV  = (u16*)(ws + OFF_WKV);
  u16*   WQB  = (u16*)(ws + OFF_WQB);
  u16*   WOB  = (u16*)(ws + OFF_WOB);
  float* BKV  = (float*)(ws + OFF_BKV);
  u16*   A3DT = (u16*)(ws + OFF_A3DT);
  u16*   Qw   = (u16*)(ws + OFF_Q);

  // large intermediates in the out1 region (overwritten by k_resize_a4 at the very end)
  char* o1 = (char*)out1;
  u16*   A4T  = (u16*)(o1 + OUT1_A4T);
  u16*   KVw  = (u16*)(o1 + OUT1_KV);
  u16*   ATT  = (u16*)(o1 + OUT1_ATT);
  u16*   PROJ = (u16*)(o1 + OUT1_PROJ);
  float* VKp  = (float*)(o1 + OUT1_VK);
  u16*   VKB  = (u16*)(o1 + OUT1_VKB);

  // weight prep
  k_fold<<<512, 256, 0, stream>>>(conv_w, conv_b, bn_g, bn_b, bn_rm, bn_rv,
                                  wk, bk, wv, bv, WKV, BKV);
  k_cvt2<<<512, 256, 0, stream>>>(wq, wo, WQB, WOB);

  // input reshapes
  k_pool_a3<<<dim3(64, 8, 8), 256, 0, stream>>>(a3, A3DT);
  k_tr_a4<<<dim3(64, 16, 8), 256, 0, stream>>>(a4, A4T);

  // projections
  k_gemm<256, 256, 0><<<dim3(256, 2), 256, 0, stream>>>(A3DT, WQB, bq, (void*)Qw);
  k_gemm<512, 512, 1><<<dim3(256, 4), 256, 0, stream>>>(A4T, WKV, BKV, (void*)KVw);

  // norms (+ReLU)
  k_ln_row<<<8192, 256, 0, stream>>>(Qw, lnq_g, lnq_b);
  k_ln_col<<<dim3(32, 8), 256, 0, stream>>>(KVw, lnk_g, lnk_b);

  // attention (deterministic: per-chunk partials + reduction, no atomics/memset)
  k_vk<<<dim3(16, 64), 64, 0, stream>>>(KVw, VKp);
  k_cvt_vk<<<384, 256, 0, stream>>>(VKp, VKB);
  k_att<<<dim3(16, 64), 256, 0, stream>>>(Qw, VKB, ATT);

  // output projection (channel-major bf16)
  k_gemm<256, 256, 1><<<dim3(256, 2), 256, 0, stream>>>(ATT, WOB, bo, (void*)PROJ);

  // outputs
  k_resize_mul_a3<<<2048, 256, 0, stream>>>(PROJ, a3, out0);
  k_resize_a4<<<4096, 256, 0, stream>>>(a4, out1);
}

// Round 5
// 774.852 us; speedup vs baseline: 1.0338x; 1.0138x over previous
//
#include <hip/hip_runtime.h>
#include <cstdint>
#include <cstddef>

typedef unsigned short u16;
typedef __bf16 bf16x8 __attribute__((ext_vector_type(8)));
typedef float f32x4 __attribute__((ext_vector_type(4)));

#define EPS_ 1e-5f

// ---------- helpers ----------
__device__ __forceinline__ float bf2f(u16 u){
  union { uint32_t i; float f; } v; v.i = ((uint32_t)u) << 16; return v.f;
}
__device__ __forceinline__ u16 f2bf(float f){
  union { float f; uint32_t i; } v; v.f = f;
  uint32_t u = v.i;
  u += 0x7fffu + ((u >> 16) & 1u);   // round-to-nearest-even
  return (u16)(u >> 16);
}
__device__ __forceinline__ void gload_lds16(const void* g, void* l){
  __builtin_amdgcn_global_load_lds((const __attribute__((address_space(1))) uint32_t*)g,
                                   (__attribute__((address_space(3))) uint32_t*)l, 16, 0, 0);
}

// ---------- workspace offsets (bytes) — small buffers only ----------
#define OFF_WKV   ((size_t)0)            // 512*512*2 = 524288
#define OFF_WQB   ((size_t)524288)       // 131072
#define OFF_WOB   ((size_t)655360)       // 131072
#define OFF_BKV   ((size_t)786432)       // 2048 (pad)
#define OFF_A3DT  ((size_t)2097152)      // 32768*256*2 = 16777216
#define OFF_Q     ((size_t)18874368)     // 16777216  (end 35651584)

// large intermediates live in d_out's out1 region (268 MB, guaranteed size);
// k_resize_a4 overwrites the whole region LAST, after every reader finished (stream order)
#define OUT1_A4T  ((size_t)0)            // 33554432
#define OUT1_KV   ((size_t)33554432)     // 33554432
#define OUT1_ATT  ((size_t)67108864)     // 16777216
#define OUT1_PROJ ((size_t)83886080)     // 16777216 (bf16)
#define OUT1_VK   ((size_t)117440512)    // 64bh*32pc*1056*4 = 8650752 (f32 chunk partials)
#define OUT1_VKB  ((size_t)126091264)    // 64*48*32*2 = 196608   end 126287872 < 268435456

// ---------- weight folding (blocks 0..511) + wq/wo bf16 convert (blocks 512..1023) ----------
__global__ __launch_bounds__(256) void k_fold(
    const float* __restrict__ conv_w, const float* __restrict__ conv_b,
    const float* __restrict__ bn_g, const float* __restrict__ bn_b,
    const float* __restrict__ bn_rm, const float* __restrict__ bn_rv,
    const float* __restrict__ wk, const float* __restrict__ bk,
    const float* __restrict__ wv, const float* __restrict__ bv,
    const float* __restrict__ wq, const float* __restrict__ wo,
    u16* __restrict__ WKV, float* __restrict__ bkv,
    u16* __restrict__ WQB, u16* __restrict__ WOB){
  int n = blockIdx.x;
  int t = threadIdx.x;
  if (n >= 512){  // convert wq (512..767) / wo (768..1023)
    const float* src = (n < 768) ? wq : wo;
    u16* dst = (n < 768) ? WQB : WOB;
    int i = (n & 255)*256 + t;
    dst[i] = f2bf(src[i]);
    return;
  }
  const float* wrow = (n < 256) ? (wk + (size_t)n*256) : (wv + (size_t)(n-256)*256);
  __shared__ float sw[256], st_[256];
  {
    float s  = bn_g[t] * rsqrtf(bn_rv[t] + EPS_);
    float tt = s * (conv_b[t] - bn_rm[t]) + bn_b[t];
    float w = wrow[t];
    sw[t] = w * s;
    st_[t] = w * tt;
  }
  __syncthreads();
  for (int cc = 0; cc < 2; ++cc){
    int c = t + cc*256;
    float acc = 0.f;
    #pragma unroll 8
    for (int o = 0; o < 256; ++o)
      acc += sw[o] * conv_w[(size_t)o*512 + c];
    WKV[(size_t)n*512 + c] = f2bf(acc);
  }
  if (t == 0){
    float acc = (n < 256) ? bk[n] : bv[n-256];
    for (int o = 0; o < 256; ++o) acc += st_[o];
    bkv[n] = acc;
  }
}

// ---------- a3 2x2 avg-pool + transpose to [b, p, c] bf16 ----------
__global__ __launch_bounds__(256) void k_pool_a3(const float* __restrict__ a3, u16* __restrict__ a3dT){
  int y = blockIdx.x;            // 0..63
  int c0 = blockIdx.y * 32;      // 8 tiles
  int b = blockIdx.z;
  int t = threadIdx.x;
  __shared__ float ld[32*257];
  const float* src = a3 + (((size_t)(b*256 + c0))*128 + 2*y)*128;
  #pragma unroll
  for (int cc = 0; cc < 32; ++cc)
    ld[cc*257 + t] = src[(size_t)cc*16384 + t];   // rows 2y,2y+1 contiguous (256 floats)
  __syncthreads();
  int cc = t & 31, xb = t >> 5;
  u16* dst = a3dT + ((size_t)b*4096 + y*64)*256 + c0 + cc;
  #pragma unroll
  for (int xi = 0; xi < 8; ++xi){
    int x = xb*8 + xi;
    const float* r = &ld[cc*257 + 2*x];
    float v = 0.25f*(r[0] + r[1] + r[128] + r[129]);
    dst[(size_t)x*256] = f2bf(v);
  }
}

// ---------- a4 transpose to [b, p, c] bf16 ----------
__global__ __launch_bounds__(256) void k_tr_a4(const float* __restrict__ a4, u16* __restrict__ a4T){
  int y = blockIdx.x;            // 0..63
  int c0 = blockIdx.y * 32;      // 16 tiles
  int b = blockIdx.z;
  int t = threadIdx.x;
  __shared__ float ld[32*65];
  const float* src = a4 + (((size_t)(b*512 + c0))*64 + y)*64;
  #pragma unroll
  for (int i = 0; i < 8; ++i){
    int idx = i*256 + t;
    int cc = idx >> 6, x = idx & 63;
    ld[cc*65 + x] = src[(size_t)cc*4096 + x];
  }
  __syncthreads();
  int cc = t & 31, xb = t >> 5;
  u16* dst = a4T + ((size_t)b*4096 + y*64)*512 + c0 + cc;
  #pragma unroll
  for (int xi = 0; xi < 8; ++xi){
    int x = xb*8 + xi;
    dst[(size_t)x*512] = f2bf(ld[cc*65 + x]);
  }
}

// ---------- bf16 MFMA GEMM: C[m,n] = A[m,:]·Bw[n,:] + bias[n] ----------
// SMODE 0: pos-major bf16 C[m*N + n]
// SMODE 1: channel-major bf16 C[(b*N + n)*4096 + p]   (m = b*4096 + p)
template<int KDIM, int NDIM, int SMODE>
__global__ __launch_bounds__(256) void k_gemm(
    const u16* __restrict__ A, const u16* __restrict__ Bw,
    const float* __restrict__ bias, void* __restrict__ Cout){
  __shared__ alignas(16) u16 lA[128*32];
  __shared__ alignas(16) u16 lB[128*32];
  int m0 = blockIdx.x * 128, n0 = blockIdx.y * 128;
  int t = threadIdx.x;
  int lane = t & 63, wid = t >> 6;
  int wm = wid >> 1, wn = wid & 1;
  int fr = lane & 15, fq = lane >> 4;
  f32x4 acc[4][4] = {};
  const u16* Abase = A + (size_t)m0 * KDIM;
  const u16* Bbase = Bw + (size_t)n0 * KDIM;
  for (int kt = 0; kt < KDIM/32; ++kt){
    #pragma unroll
    for (int i = 0; i < 2; ++i){
      int u = i*256 + t;       // 16B unit within 8KB tile
      gload_lds16(Abase + (size_t)(u>>2)*KDIM + kt*32 + (u&3)*8, lA + u*8);
      gload_lds16(Bbase + (size_t)(u>>2)*KDIM + kt*32 + (u&3)*8, lB + u*8);
    }
    __syncthreads();
    bf16x8 af[4], bfr[4];
    #pragma unroll
    for (int fm = 0; fm < 4; ++fm)
      af[fm] = *(const bf16x8*)&lA[(wm*64 + fm*16 + fr)*32 + fq*8];
    #pragma unroll
    for (int fn = 0; fn < 4; ++fn)
      bfr[fn] = *(const bf16x8*)&lB[(wn*64 + fn*16 + fr)*32 + fq*8];
    #pragma unroll
    for (int fm = 0; fm < 4; ++fm)
      #pragma unroll
      for (int fn = 0; fn < 4; ++fn)
        acc[fm][fn] = __builtin_amdgcn_mfma_f32_16x16x32_bf16(af[fm], bfr[fn], acc[fm][fn], 0, 0, 0);
    __syncthreads();
  }
  #pragma unroll
  for (int fn = 0; fn < 4; ++fn){
    int j = n0 + wn*64 + fn*16 + fr;
    float bj = bias[j];
    #pragma unroll
    for (int fm = 0; fm < 4; ++fm){
      int m = m0 + wm*64 + fm*16 + fq*4;
      if constexpr (SMODE == 0){
        u16* C = (u16*)Cout;
        #pragma unroll
        for (int i = 0; i < 4; ++i)
          C[(size_t)(m + i)*NDIM + j] = f2bf(acc[fm][fn][i] + bj);
      } else {
        int b = m >> 12, p = m & 4095;
        size_t base = ((size_t)(b*NDIM + j))*4096 + p;
        u16* C = (u16*)Cout;
        ushort4 pk;
        pk.x = f2bf(acc[fm][fn][0] + bj);
        pk.y = f2bf(acc[fm][fn][1] + bj);
        pk.z = f2bf(acc[fm][fn][2] + bj);
        pk.w = f2bf(acc[fm][fn][3] + bj);
        *(ushort4*)&C[base] = pk;
      }
    }
  }
}

// ---------- LayerNorm+ReLU, row-major [32768, 256], in place ----------
__global__ __launch_bounds__(256) void k_ln_row(u16* __restrict__ X,
    const float* __restrict__ g, const float* __restrict__ bb){
  int row = blockIdx.x*4 + (threadIdx.x >> 6);
  int lane = threadIdx.x & 63;
  u16* p = X + (size_t)row*256 + lane*4;
  ushort4 v4 = *(const ushort4*)p;
  float v0 = bf2f(v4.x), v1 = bf2f(v4.y), v2 = bf2f(v4.z), v3 = bf2f(v4.w);
  float s = v0+v1+v2+v3;
  float s2 = v0*v0+v1*v1+v2*v2+v3*v3;
  #pragma unroll
  for (int off = 32; off > 0; off >>= 1){
    s  += __shfl_down(s, off);
    s2 += __shfl_down(s2, off);
  }
  s = __shfl(s, 0); s2 = __shfl(s2, 0);
  float mean = s * (1.f/256.f);
  float var = s2 * (1.f/256.f) - mean*mean;
  float r = rsqrtf(var + EPS_);
  float4 gg = *(const float4*)&g[lane*4];
  float4 b4 = *(const float4*)&bb[lane*4];
  ushort4 o;
  o.x = f2bf(fmaxf((v0-mean)*r*gg.x + b4.x, 0.f));
  o.y = f2bf(fmaxf((v1-mean)*r*gg.y + b4.y, 0.f));
  o.z = f2bf(fmaxf((v2-mean)*r*gg.z + b4.z, 0.f));
  o.w = f2bf(fmaxf((v3-mean)*r*gg.w + b4.w, 0.f));
  *(ushort4*)p = o;
}

// ---------- FUSED: column-LN+ReLU on K (in LDS, no write-back) + VK partials + denominator ----------
// grid (32 p-chunks, 8 b), 256 threads. LDS K-tile [256 j][136 u16] (stride 68 u32, 16B-aligned rows).
__global__ __launch_bounds__(256) void k_lnvk(const u16* __restrict__ KV,
    const float* __restrict__ g, const float* __restrict__ bb, float* __restrict__ VKp){
  int pc = blockIdx.x;
  int p0 = pc * 128;
  int b = blockIdx.y;
  int t = threadIdx.x;
  __shared__ uint32_t lds32[256*68];     // 69632 B
  __shared__ float sA[256], sB[256];
  __shared__ float meanA[128], rstdA[128];
  __shared__ float sG[256], sBb[256];
  u16* tile = (u16*)lds32;
  sG[t] = g[t]; sBb[t] = bb[t];
  int rg = t >> 4;          // row-in-group 0..15
  int l16 = t & 15;         // 16-lane col group
  // load K-half [256 j][128 p] via uint4 (16B/lane)
  #pragma unroll 4
  for (int i = 0; i < 16; ++i){
    int j = i*16 + rg;
    uint4 v = *(const uint4*)(KV + ((size_t)(b*512 + j))*4096 + p0 + l16*8);
    *(uint4*)&lds32[j*68 + l16*4] = v;
  }
  __syncthreads();
  // stats: thread owns p = t&127, half jh = t>>7 (128 j each)
  {
    int p = t & 127, jh = t >> 7;
    float s = 0.f, s2 = 0.f;
    #pragma unroll 8
    for (int jj = 0; jj < 128; ++jj){
      float v = bf2f(tile[(jh*128 + jj)*136 + p]);
      s += v; s2 += v*v;
    }
    sA[t] = s; sB[t] = s2;
  }
  __syncthreads();
  if (t < 128){
    float st = sA[t] + sA[128 + t];
    float s2t = sB[t] + sB[128 + t];
    float mean = st * (1.f/256.f);
    float var = s2t * (1.f/256.f) - mean*mean;
    meanA[t] = mean;
    rstdA[t] = rsqrtf(var + EPS_);
  }
  __syncthreads();
  // normalize + ReLU in LDS; thread's 8 p-cols fixed -> preload stats
  float mm[8], rr[8];
  #pragma unroll
  for (int k = 0; k < 8; ++k){
    mm[k] = meanA[l16*8 + k];
    rr[k] = rstdA[l16*8 + k];
  }
  #pragma unroll 4
  for (int i = 0; i < 16; ++i){
    int j = i*16 + rg;
    uint32_t* rowp = &lds32[j*68 + l16*4];
    uint4 v = *(uint4*)rowp;
    float gj = sG[j], bj = sBb[j];
    uint32_t w_[4] = {v.x, v.y, v.z, v.w};
    #pragma unroll
    for (int w2 = 0; w2 < 4; ++w2){
      float v0 = bf2f((u16)(w_[w2] & 0xffffu));
      float v1 = bf2f((u16)(w_[w2] >> 16));
      u16 o0 = f2bf(fmaxf((v0 - mm[2*w2])*rr[2*w2]*gj + bj, 0.f));
      u16 o1 = f2bf(fmaxf((v1 - mm[2*w2+1])*rr[2*w2+1]*gj + bj, 0.f));
      w_[w2] = (uint32_t)o0 | ((uint32_t)o1 << 16);
    }
    uint4 ov; ov.x = w_[0]; ov.y = w_[1]; ov.z = w_[2]; ov.w = w_[3];
    *(uint4*)rowp = ov;
  }
  __syncthreads();
  // VK MFMAs: wave wid handles heads {2*wid, 2*wid+1}; V fragments direct from global
  int lane = t & 63, wid = t >> 6;
  int fr = lane & 15, fq = lane >> 4;
  #pragma unroll
  for (int hh = 0; hh < 2; ++hh){
    int h = wid*2 + hh;
    f32x4 acc[2][2] = {};
    #pragma unroll
    for (int ks = 0; ks < 4; ++ks){
      bf16x8 kf0 = *(const bf16x8*)&tile[(h*32 + fr)*136 + ks*32 + fq*8];
      bf16x8 kf1 = *(const bf16x8*)&tile[(h*32 + 16 + fr)*136 + ks*32 + fq*8];
      const u16* Vb = KV + ((size_t)(b*512 + 256 + h*32 + fr))*4096 + p0 + ks*32 + fq*8;
      bf16x8 vf0 = *(const bf16x8*)Vb;
      bf16x8 vf1 = *(const bf16x8*)(Vb + (size_t)16*4096);
      acc[0][0] = __builtin_amdgcn_mfma_f32_16x16x32_bf16(vf0, kf0, acc[0][0], 0,0,0);
      acc[0][1] = __builtin_amdgcn_mfma_f32_16x16x32_bf16(vf0, kf1, acc[0][1], 0,0,0);
      acc[1][0] = __builtin_amdgcn_mfma_f32_16x16x32_bf16(vf1, kf0, acc[1][0], 0,0,0);
      acc[1][1] = __builtin_amdgcn_mfma_f32_16x16x32_bf16(vf1, kf1, acc[1][1], 0,0,0);
    }
    float* dst = VKp + (((size_t)(b*8 + h))*32 + pc)*1056;
    #pragma unroll
    for (int et = 0; et < 2; ++et)
      #pragma unroll
      for (int dt = 0; dt < 2; ++dt)
        #pragma unroll
        for (int i = 0; i < 4; ++i){
          int e = et*16 + fq*4 + i;
          int d = dt*16 + fr;
          dst[e*32 + d] = acc[et][dt][i];
        }
  }
  // denominator partial: thread (h = t>>5, d = t&31) sums K'[h*32+d, p-chunk]
  {
    int h = t >> 5, d = t & 31;
    int j = h*32 + d;
    float s = 0.f;
    #pragma unroll 8
    for (int i = 0; i < 64; ++i){
      uint32_t x = lds32[j*68 + i];
      s += bf2f((u16)(x & 0xffffu)) + bf2f((u16)(x >> 16));
    }
    VKp[(((size_t)(b*8 + h))*32 + pc)*1056 + 32*32 + d] = s;
  }
}

// ---------- reduce 32 chunk partials, convert to bf16 [bh][48][32] (rows 33..47 zero) ----------
__global__ __launch_bounds__(256) void k_cvt_vk(const float* __restrict__ VKp, u16* __restrict__ VKb){
  int i = blockIdx.x*256 + threadIdx.x;   // 64*48*32
  int bh = i / (48*32);
  int r = i - bh*48*32;
  int e = r >> 5, d = r & 31;
  float v = 0.f;
  if (e < 33){
    const float* p = VKp + (size_t)bh*32*1056 + e*32 + d;
    #pragma unroll
    for (int c = 0; c < 32; ++c) v += p[(size_t)c*1056];
  }
  VKb[i] = f2bf(v);
}

// ---------- out = (VK·Q)/denom with the torch-faithful scrambled store ----------
__global__ __launch_bounds__(256) void k_att(const u16* __restrict__ Q,
    const u16* __restrict__ VKb, u16* __restrict__ ATT){
  int qc = blockIdx.x;     // 16 q-chunks of 256
  int bh = blockIdx.y;     // 64
  int b = bh >> 3, h = bh & 7;
  int t = threadIdx.x;
  int lane = t & 63, wid = t >> 6;
  int fr = lane & 15, fq = lane >> 4;
  int q0 = qc*256 + wid*64;
  const u16* Qb = Q + ((size_t)(b*4096 + q0))*256 + h*32 + fq*8;
  bf16x8 aq[4];
  #pragma unroll
  for (int fm = 0; fm < 4; ++fm)
    aq[fm] = *(const bf16x8*)&Qb[(size_t)(fm*16 + fr)*256];
  const u16* Vb = VKb + (size_t)bh*48*32;
  bf16x8 bv_[3];
  #pragma unroll
  for (int fn = 0; fn < 3; ++fn)
    bv_[fn] = *(const bf16x8*)&Vb[(fn*16 + fr)*32 + fq*8];
  f32x4 acc[4][3] = {};
  #pragma unroll
  for (int fm = 0; fm < 4; ++fm)
    #pragma unroll
    for (int fn = 0; fn < 3; ++fn)
      acc[fm][fn] = __builtin_amdgcn_mfma_f32_16x16x32_bf16(aq[fm], bv_[fn], acc[fm][fn], 0,0,0);
  __shared__ alignas(16) u16 latt[32*264];
  #pragma unroll
  for (int fm = 0; fm < 4; ++fm){
    #pragma unroll
    for (int i = 0; i < 4; ++i){
      float dv = __shfl(acc[fm][2][i], lane & 48);   // e=32 value lives in fr==0 lane of my fq group
      float rd = 1.0f / fmaxf(dv, EPS_);
      int qloc = wid*64 + fm*16 + fq*4 + i;
      latt[(fr)*264 + qloc]      = f2bf(acc[fm][0][i] * rd);
      latt[(16 + fr)*264 + qloc] = f2bf(acc[fm][1][i] * rd);
    }
  }
  __syncthreads();
  // scrambled reshape: (e,h,q) -> row 128e + 16h + (q>>8), col q&255
  int row = t >> 3, seg = t & 7;
  u16* dst = ATT + ((size_t)(b*4096 + row*128 + h*16 + qc))*256 + seg*32;
  const u16* srcl = &latt[row*264 + seg*32];
  #pragma unroll
  for (int k = 0; k < 4; ++k)
    *(uint4*)&dst[k*8] = *(const uint4*)&srcl[k*8];
}

// ---------- bilinear 2x upsample (jax half-pixel, edge-renormalized) ----------
__device__ __forceinline__ void bil_idx(int o, int n, int &i0, int &i1, float &w0, float &w1){
  float s = 0.5f*(float)o - 0.25f;
  float fl = floorf(s);
  i0 = (int)fl; i1 = i0 + 1;
  w1 = s - fl; w0 = 1.f - w1;
  if (i0 < 0){ i0 = 0; w0 = 0.f; w1 = 1.f; }
  if (i1 > n-1){ i1 = n-1; w1 = 0.f; w0 = 1.f; }
}

__global__ __launch_bounds__(256) void k_resize_mul_a3(const u16* __restrict__ PROJ,
    const float* __restrict__ a3, float* __restrict__ out0){
  int bc = blockIdx.x;   // b*256 + ch
  int t = threadIdx.x;
  __shared__ float P[4096];
  const uint32_t* src = (const uint32_t*)(PROJ + (size_t)bc*4096);
  #pragma unroll
  for (int i = 0; i < 8; ++i){
    uint32_t v = src[i*256 + t];
    P[(i*256 + t)*2]     = bf2f((u16)(v & 0xffffu));
    P[(i*256 + t)*2 + 1] = bf2f((u16)(v >> 16));
  }
  __syncthreads();
  const float* ap = a3 + (size_t)bc*16384;
  float* op = out0 + (size_t)bc*16384;
  for (int k = 0; k < 64; ++k){
    int px = k*256 + t;
    int Y = px >> 7, X = px & 127;
    int y0,y1,x0,x1; float wy0,wy1,wx0,wx1;
    bil_idx(Y, 64, y0,y1,wy0,wy1);
    bil_idx(X, 64, x0,x1,wx0,wx1);
    float v = wy0*(wx0*P[y0*64+x0] + wx1*P[y0*64+x1])
            + wy1*(wx0*P[y1*64+x0] + wx1*P[y1*64+x1]);
    op[px] = v * ap[px];
  }
}

__global__ __launch_bounds__(256) void k_resize_a4(const float* __restrict__ a4, float* __restrict__ out1){
  int bc = blockIdx.x;   // b*512 + c
  int t = threadIdx.x;
  __shared__ float P[4096];
  const float* src = a4 + (size_t)bc*4096;
  #pragma unroll
  for (int i = 0; i < 16; ++i) P[i*256 + t] = src[i*256 + t];
  __syncthreads();
  float* op = out1 + (size_t)bc*16384;
  for (int k = 0; k < 64; ++k){
    int px = k*256 + t;
    int Y = px >> 7, X = px & 127;
    int y0,y1,x0,x1; float wy0,wy1,wx0,wx1;
    bil_idx(Y, 64, y0,y1,wy0,wy1);
    bil_idx(X, 64, x0,x1,wx0,wx1);
    op[px] = wy0*(wx0*P[y0*64+x0] + wx1*P[y0*64+x1])
           + wy1*(wx0*P[y1*64+x0] + wx1*P[y1*64+x1]);
  }
}

// ---------- host launch ----------
extern "C" void kernel_launch(void* const* d_in, const int* in_sizes, int n_in,
                              void* d_out, int out_size, void* d_ws, size_t ws_size,
                              hipStream_t stream){
  (void)in_sizes; (void)n_in; (void)out_size; (void)ws_size;
  const float* a3     = (const float*)d_in[0];
  const float* a4     = (const float*)d_in[1];
  const float* conv_w = (const float*)d_in[2];
  const float* conv_b = (const float*)d_in[3];
  const float* bn_g   = (const float*)d_in[4];
  const float* bn_b   = (const float*)d_in[5];
  const float* bn_rm  = (const float*)d_in[6];
  const float* bn_rv  = (const float*)d_in[7];
  const float* wq     = (const float*)d_in[8];
  const float* bq     = (const float*)d_in[9];
  const float* lnq_g  = (const float*)d_in[10];
  const float* lnq_b  = (const float*)d_in[11];
  const float* wk     = (const float*)d_in[12];
  const float* bk     = (const float*)d_in[13];
  const float* lnk_g  = (const float*)d_in[14];
  const float* lnk_b  = (const float*)d_in[15];
  const float* wv     = (const float*)d_in[16];
  const float* bv     = (const float*)d_in[17];
  const float* wo     = (const float*)d_in[18];
  const float* bo     = (const float*)d_in[19];
  // d_in[20..27] (FFN weights/norms) are dead code in the reference; d_in[28] = idx (always 11)

  float* out0 = (float*)d_out;
  float* out1 = out0 + (size_t)33554432;

  char* ws = (char*)d_ws;
  u16*   WKV  = (u16*)(ws + OFF_WKV);
  u16*   WQB  = (u16*)(ws + OFF_WQB);
  u16*   WOB  = (u16*)(ws + OFF_WOB);
  float* BKV  = (float*)(ws + OFF_BKV);
  u16*   A3DT = (u16*)(ws + OFF_A3DT);
  u16*   Qw   = (u16*)(ws + OFF_Q);

  // large intermediates in the out1 region (overwritten by k_resize_a4 at the very end)
  char* o1 = (char*)out1;
  u16*   A4T  = (u16*)(o1 + OUT1_A4T);
  u16*   KVw  = (u16*)(o1 + OUT1_KV);
  u16*   ATT  = (u16*)(o1 + OUT1_ATT);
  u16*   PROJ = (u16*)(o1 + OUT1_PROJ);
  float* VKp  = (float*)(o1 + OUT1_VK);
  u16*   VKB  = (u16*)(o1 + OUT1_VKB);

  // weight prep (fold conv+BN into K/V weights; convert wq/wo)
  k_fold<<<1024, 256, 0, stream>>>(conv_w, conv_b, bn_g, bn_b, bn_rm, bn_rv,
                                   wk, bk, wv, bv, wq, wo, WKV, BKV, WQB, WOB);

  // input reshapes
  k_pool_a3<<<dim3(64, 8, 8), 256, 0, stream>>>(a3, A3DT);
  k_tr_a4<<<dim3(64, 16, 8), 256, 0, stream>>>(a4, A4T);

  // projections
  k_gemm<256, 256, 0><<<dim3(256, 2), 256, 0, stream>>>(A3DT, WQB, bq, (void*)Qw);
  k_gemm<512, 512, 1><<<dim3(256, 4), 256, 0, stream>>>(A4T, WKV, BKV, (void*)KVw);

  // Q norm (+ReLU)
  k_ln_row<<<8192, 256, 0, stream>>>(Qw, lnq_g, lnq_b);

  // fused K column-LN (+ReLU, LDS-only) + VK partials + denominator
  k_lnvk<<<dim3(32, 8), 256, 0, stream>>>(KVw, lnk_g, lnk_b, VKp);
  k_cvt_vk<<<384, 256, 0, stream>>>(VKp, VKB);
  k_att<<<dim3(16, 64), 256, 0, stream>>>(Qw, VKB, ATT);

  // output projection (channel-major bf16)
  k_gemm<256, 256, 1><<<dim3(256, 2), 256, 0, stream>>>(ATT, WOB, bo, (void*)PROJ);

  // outputs
  k_resize_mul_a3<<<2048, 256, 0, stream>>>(PROJ, a3, out0);
  k_resize_a4<<<4096, 256, 0, stream>>>(a4, out1);
}